// Round 2
// baseline (1328.735 us; speedup 1.0000x reference)
//
#include <hip/hip_runtime.h>
#include <stdint.h>

#define B_ 8192
#define N_ 64
#define D_ 128
#define H_ 8
#define HD_ 16
#define L_ 3
#define F_ 512

typedef unsigned int uint;
typedef unsigned short ushort;

// ---------- bf16 helpers (bf16 == ushort) ----------
__device__ __forceinline__ float bf2f(ushort u){ union{uint i; float f;} c; c.i = ((uint)u)<<16; return c.f; }
__device__ __forceinline__ ushort f2bf(float f){           // round-to-nearest-even
  uint u = __float_as_uint(f);
  uint r = (u + 0x7fffu + ((u>>16)&1u)) >> 16;
  return (ushort)r;
}

__device__ __forceinline__ float wsum(float v){ for (int o=32;o;o>>=1) v += __shfl_xor(v,o); return v; }
__device__ __forceinline__ float wmaxr(float v){ for (int o=32;o;o>>=1) v = fmaxf(v,__shfl_xor(v,o)); return v; }

// 128-thread (2-wave) dual reduction via per-batch LDS scratch
__device__ __forceinline__ void red128(float v1, float v2, volatile float* red, int t,
                                       float& o1, float& o2){
  v1 = wsum(v1); v2 = wsum(v2);
  __syncthreads();
  if ((t&63)==0){ int w = t>>6; red[w*2] = v1; red[w*2+1] = v2; }
  __syncthreads();
  o1 = red[0]+red[2]; o2 = red[1]+red[3];
}

// ---------- prep 1: WkT'[l][j][d] = nkv_g[d]*Wk[d][j]  (transposed); bk'[j] fold ----------
__global__ void st_prep1(const float* __restrict__ Wk, const float* __restrict__ bk,
                         const float* __restrict__ nkv_g, const float* __restrict__ nkv_b,
                         ushort* __restrict__ WkT, float* __restrict__ bkF){
  __shared__ float red[2];
  const int l = blockIdx.x >> 7, j = blockIdx.x & 127, t = threadIdx.x;  // t = d
  float w = Wk[l*D_*D_ + t*D_ + j];
  WkT[l*D_*D_ + j*D_ + t] = f2bf(nkv_g[l*D_+t] * w);
  float pv = nkv_b[l*D_+t] * w;
  pv = wsum(pv);
  if ((t&63)==0) red[t>>6] = pv;
  __syncthreads();
  if (t==0) bkF[l*D_+j] = red[0]+red[1] + bk[l*D_+j];
}

// ---------- prep 2: row-scale folds Wq'(n1), Wv'(nkv), W1'(n2) + bias folds ----------
__global__ void st_prep2(const float* Wq, const float* bq, const float* n1_g, const float* n1_b,
                         const float* Wv, const float* bv, const float* nkv_g, const float* nkv_b,
                         const float* W1, const float* b1, const float* n2_g, const float* n2_b,
                         ushort* WqF, float* bqF, ushort* WvF, float* bvF, ushort* W1F, float* b1F){
  const int l = blockIdx.x / 3, m = blockIdx.x % 3, t = threadIdx.x;
  const float *W, *bias, *gg, *bb; ushort* WF; float* bF; int rowlen, elems;
  if (m==0){ W=Wq+l*D_*D_; bias=bq+l*D_; gg=n1_g+l*D_;  bb=n1_b+l*D_;  WF=WqF+l*D_*D_; bF=bqF+l*D_; rowlen=D_; elems=D_*D_; }
  else if (m==1){ W=Wv+l*D_*D_; bias=bv+l*D_; gg=nkv_g+l*D_; bb=nkv_b+l*D_; WF=WvF+l*D_*D_; bF=bvF+l*D_; rowlen=D_; elems=D_*D_; }
  else { W=W1+l*D_*F_; bias=b1+l*F_; gg=n2_g+l*D_;  bb=n2_b+l*D_;  WF=W1F+l*D_*F_; bF=b1F+l*F_; rowlen=F_; elems=D_*F_; }
  for (int idx=t; idx<elems; idx+=256){
    int d = (m==2) ? (idx>>9) : (idx>>7);
    WF[idx] = f2bf(gg[d] * W[idx]);
  }
  for (int f=t; f<rowlen; f+=256){
    float a = bias[f];
    for (int d=0; d<D_; ++d) a += bb[d] * W[d*rowlen+f];
    bF[f] = a;
  }
}

// ---------- prep 3: plain f32 -> bf16 conversion ----------
__global__ void st_cvt(const float* __restrict__ src, ushort* __restrict__ dst, int n){
  int i = blockIdx.x*256 + threadIdx.x;
  if (i < n) dst[i] = f2bf(src[i]);
}

// ---------- main fused kernel: 2 batches / 256-thread block ----------
struct P {
  const float *ego_ctx,*ego_pos,*ego_vel,*npos,*nvel;
  const int   *mask;
  const float *np_W,*np_b,*np_g,*np_bb;
  const float *ego_b,*ego_g,*ego_bb;
  const float *bo,*b2;
  const float *out_b,*out_g,*out_bb;
  const ushort *egoWB,*WoB,*W2B,*outWB;       // bf16 (ws)
  const ushort *WqF,*WkT,*WvF,*W1F;           // bf16 folded (ws)
  const float  *bqF,*bkF,*bvF,*b1F;           // f32 folded (ws)
  float *out;
};

__global__ __launch_bounds__(256,2) void st_main(P p){
  __shared__ float  s_npW[6*D_];          // 3 KB
  __shared__ float  s_npP[3*D_];          // np_b, np_ln_g, np_ln_b
  __shared__ ushort s_nbhat[2][N_*130];   // stride 130 bf16 -> conflict-free rows & cols
  __shared__ float  s_x[2][D_], s_vA[2][D_], s_vB[2][D_], s_Q[2][D_];
  __shared__ float  s_qk[2][H_*D_];       // reused as h1[512] in FFN
  __shared__ float  s_U[2][H_*D_];
  __shared__ float  s_attn[2][H_*N_];
  __shared__ float  s_valid[2][N_];
  __shared__ float  s_qb[2][H_];
  __shared__ float  s_red[2][8];

  const int tid = threadIdx.x;
  const int g = tid>>7, t = tid&127;
  const int b = blockIdx.x*2 + g;
  const float inv128 = 1.f/128.f;

  for (int i = tid; i < 6*D_; i += 256) s_npW[i] = p.np_W[i];
  if (tid < D_){ s_npP[tid] = p.np_b[tid]; s_npP[D_+tid] = p.np_g[tid]; s_npP[2*D_+tid] = p.np_bb[tid]; }

  // ---- phase 0: ego projection + LN ----
  s_vA[g][t] = p.ego_ctx[b*D_ + t];
  __syncthreads();
  float xreg;
  {
    float acc = p.ego_b[t];
    #pragma unroll 8
    for (int d=0; d<D_; ++d) acc += s_vA[g][d] * bf2f(p.egoWB[d*D_ + t]);
    float s1,s2; red128(acc, acc*acc, &s_red[g][0], t, s1, s2);
    float m = s1*inv128, rs = rsqrtf(s2*inv128 - m*m + 1e-5f);
    xreg = (acc-m)*rs*p.ego_g[t] + p.ego_bb[t];
    s_x[g][t] = xreg;
  }

  // ---- phase 1: neighbor features -> nb -> nbhat (bf16 LDS), validity ----
  {
    const int nn = t>>1, jh = t&1;
    float2 pn = ((const float2*)p.npos)[b*N_ + nn];
    float2 vn = ((const float2*)p.nvel)[b*N_ + nn];
    float2 pe = ((const float2*)p.ego_pos)[b];
    float2 ve = ((const float2*)p.ego_vel)[b];
    float rx  = pn.x-pe.x, ry  = pn.y-pe.y;
    float rvx = vn.x-ve.x, rvy = vn.y-ve.y;
    float nrm  = sqrtf(rx*rx+ry*ry);
    float dist = fmaxf(nrm, 1e-6f);
    float bear = atan2f(ry + 1e-8f, rx + 1e-8f);
    bool vld = (p.mask[b*N_ + nn] != 0) && (nrm < 3.0f);
    if (jh==0) s_valid[g][nn] = vld ? 1.f : 0.f;

    float z[64]; float sa=0.f, sb=0.f;
    #pragma unroll
    for (int jj=0; jj<64; ++jj){
      int j = jh*64 + jj;
      float v = s_npP[j] + rx*s_npW[j] + ry*s_npW[D_+j] + rvx*s_npW[2*D_+j]
                         + rvy*s_npW[3*D_+j] + dist*s_npW[4*D_+j] + bear*s_npW[5*D_+j];
      z[jj]=v; sa+=v; sb+=v*v;
    }
    sa += __shfl_xor(sa,1); sb += __shfl_xor(sb,1);
    float mm = sa*inv128, rr = rsqrtf(sb*inv128 - mm*mm + 1e-5f);
    float ta=0.f, tb=0.f;
    #pragma unroll
    for (int jj=0; jj<64; ++jj){
      int j = jh*64 + jj;
      float a = (z[jj]-mm)*rr*s_npP[D_+j] + s_npP[2*D_+j];
      a = fmaxf(a, 0.f);
      z[jj]=a; ta+=a; tb+=a*a;
    }
    ta += __shfl_xor(ta,1); tb += __shfl_xor(tb,1);
    float m2 = ta*inv128, r2 = rsqrtf(tb*inv128 - m2*m2 + 1e-5f);
    uint* dst = (uint*)&s_nbhat[g][nn*130 + jh*64];
    #pragma unroll
    for (int q=0; q<32; ++q){
      ushort lo = f2bf((z[2*q  ]-m2)*r2);
      ushort hi = f2bf((z[2*q+1]-m2)*r2);
      dst[q] = (uint)lo | ((uint)hi<<16);
    }
  }
  __syncthreads();

  // ---- layers ----
  for (int li=0; li<L_; ++li){
    const ushort* Wq  = p.WqF + li*D_*D_;
    const ushort* WkT = p.WkT + li*D_*D_;
    const ushort* Wv  = p.WvF + li*D_*D_;
    const ushort* W1  = p.W1F + li*D_*F_;
    const ushort* Wo  = p.WoB + li*D_*D_;
    const ushort* W2  = p.W2B + li*F_*D_;
    const float*  bq  = p.bqF + li*D_;
    const float*  bkf = p.bkF + li*D_;
    const float*  bvf = p.bvF + li*D_;
    const float*  b1f = p.b1F + li*F_;
    const float*  bo  = p.bo  + li*D_;
    const float*  b2b = p.b2  + li*D_;
    float s1,s2,m,rs;

    // (a) xhat = normalize(x)   (n1 affine folded into Wq'/bq')
    red128(xreg, xreg*xreg, &s_red[g][0], t, s1, s2);
    m = s1*inv128; rs = rsqrtf(s2*inv128 - m*m + 1e-5f);
    s_vA[g][t] = (xreg-m)*rs;
    __syncthreads();

    // (b) Q = xhat @ Wq' + bq'
    {
      float qa = bq[t];
      #pragma unroll 8
      for (int d=0; d<D_; ++d) qa += s_vA[g][d]*bf2f(Wq[d*D_+t]);
      s_Q[g][t] = qa;
    }
    __syncthreads();
    // qk[h][d] = sum_j WkT'[h*16+j][d]*Q[h*16+j];  qb[h] = Q[slice]·bk'[slice]
    #pragma unroll
    for (int h=0; h<H_; ++h){
      float a = 0.f;
      #pragma unroll
      for (int j=0; j<HD_; ++j) a += bf2f(WkT[(h*HD_+j)*D_ + t]) * s_Q[g][h*HD_+j];
      s_qk[g][h*D_ + t] = a;
    }
    if (t < H_){
      float a = 0.f;
      for (int j=0; j<HD_; ++j) a += s_Q[g][t*HD_+j]*bkf[t*HD_+j];
      s_qb[g][t] = a;
    }
    __syncthreads();

    // (c) scores + masked softmax; wave = 64 lanes = 64 neighbors; waves split heads 4+4
    {
      const int n = t&63, hb = (t>>6)*4;
      uint row[64];
      #pragma unroll
      for (int q=0; q<64; ++q) row[q] = *(const uint*)&s_nbhat[g][n*130 + 2*q];
      bool vflag = s_valid[g][n] > 0.5f;
      unsigned long long bal = __ballot(vflag);
      if (bal == 0ULL) vflag = (n==0);     // all-masked fixup
      #pragma unroll
      for (int hh=0; hh<4; ++hh){
        int h = hb+hh;
        const float2* qk2 = (const float2*)&s_qk[g][h*D_];
        float a = 0.f;
        #pragma unroll
        for (int q=0; q<64; ++q){
          float2 w = qk2[q];
          uint pr = row[q];
          union{uint i; float f;} lo, hi;
          lo.i = pr<<16; hi.i = pr & 0xffff0000u;
          a += lo.f*w.x + hi.f*w.y;
        }
        float sc = 0.25f*(a + s_qb[g][h]);   // scale = 1/sqrt(16)
        sc = vflag ? sc : -1e9f;
        float mx = wmaxr(sc);
        float e  = __expf(sc - mx);
        float se = wsum(e);
        s_attn[g][h*N_ + n] = e/se;
      }
    }
    __syncthreads();

    // (d) U[h] = sum_n attn[h][n]*nbhat[n]   (thread = (d-pair, head-half))
    {
      const int dp = t&63, hh = t>>6;
      float u[8] = {0,0,0,0,0,0,0,0};
      #pragma unroll 4
      for (int n=0; n<N_; ++n){
        uint pr = *(const uint*)&s_nbhat[g][n*130 + 2*dp];
        union{uint i; float f;} lo, hi;
        lo.i = pr<<16; hi.i = pr & 0xffff0000u;
        #pragma unroll
        for (int h4=0; h4<4; ++h4){
          float av = s_attn[g][(hh*4+h4)*N_ + n];
          u[h4*2]   += av*lo.f;
          u[h4*2+1] += av*hi.f;
        }
      }
      #pragma unroll
      for (int h4=0; h4<4; ++h4){
        s_U[g][(hh*4+h4)*D_ + 2*dp]   = u[h4*2];
        s_U[g][(hh*4+h4)*D_ + 2*dp+1] = u[h4*2+1];
      }
    }
    __syncthreads();

    // (e) ctx[j] = U[h(j)] @ Wv'[:,j] + bv'[j]
    {
      const int h = t>>4;
      float a = bvf[t];
      #pragma unroll 8
      for (int d=0; d<D_; ++d) a += s_U[g][h*D_+d]*bf2f(Wv[d*D_+t]);
      s_vB[g][t] = a;
    }
    __syncthreads();

    // (f) x += ctx @ Wo + bo
    {
      float a = bo[t];
      #pragma unroll 8
      for (int d=0; d<D_; ++d) a += s_vB[g][d]*bf2f(Wo[d*D_+t]);
      xreg += a;
    }

    // (g) yhat = normalize(x)   (n2 affine folded into W1'/b1')
    red128(xreg, xreg*xreg, &s_red[g][0], t, s1, s2);
    m = s1*inv128; rs = rsqrtf(s2*inv128 - m*m + 1e-5f);
    s_vA[g][t] = (xreg-m)*rs;
    __syncthreads();

    // (h) h1 = gelu(yhat @ W1' + b1')  -> reuse s_qk as h1[512]
    #pragma unroll
    for (int fb=0; fb<4; ++fb){
      int f = fb*128 + t;
      float a = b1f[f];
      #pragma unroll 8
      for (int d=0; d<D_; ++d) a += s_vA[g][d]*bf2f(W1[d*F_+f]);
      s_qk[g][f] = 0.5f*a*(1.f + erff(a*0.70710678118654752f));  // exact gelu
    }
    __syncthreads();

    // (i) x += h1 @ W2 + b2
    {
      float a = b2b[t];
      #pragma unroll 8
      for (int f=0; f<F_; ++f) a += s_qk[g][f]*bf2f(W2[f*D_+t]);
      xreg += a;
      s_x[g][t] = xreg;
    }
    __syncthreads();
  }

  // ---- output: LN(x @ out_W + out_b) ----
  {
    float a = p.out_b[t];
    #pragma unroll 8
    for (int d=0; d<D_; ++d) a += s_x[g][d]*bf2f(p.outWB[d*D_+t]);
    float s1,s2; red128(a, a*a, &s_red[g][0], t, s1, s2);
    float m = s1*inv128, rs = rsqrtf(s2*inv128 - m*m + 1e-5f);
    float o = (a-m)*rs*p.out_g[t] + p.out_bb[t];
    p.out[b*D_ + t] = o;
  }
}

extern "C" void kernel_launch(void* const* d_in, const int* in_sizes, int n_in,
                              void* d_out, int out_size, void* d_ws, size_t ws_size,
                              hipStream_t stream){
  (void)in_sizes; (void)n_in; (void)out_size; (void)ws_size;
  char* ws = (char*)d_ws;
  ushort* WqF   = (ushort*)(ws + 0);        // 3*16384 bf16
  ushort* WkT   = (ushort*)(ws + 98304);
  ushort* WvF   = (ushort*)(ws + 196608);
  ushort* W1F   = (ushort*)(ws + 294912);   // 3*65536 bf16
  ushort* WoB   = (ushort*)(ws + 688128);
  ushort* W2B   = (ushort*)(ws + 786432);
  ushort* egoWB = (ushort*)(ws + 1179648);
  ushort* outWB = (ushort*)(ws + 1212416);
  float*  bqF   = (float*)(ws + 1245184);
  float*  bkF   = (float*)(ws + 1246720);
  float*  bvF   = (float*)(ws + 1248256);
  float*  b1F   = (float*)(ws + 1249792);  // ends ~1.26 MB

  st_prep1<<<L_*D_, 128, 0, stream>>>((const float*)d_in[22], (const float*)d_in[23],
                                      (const float*)d_in[16], (const float*)d_in[17], WkT, bkF);
  st_prep2<<<L_*3, 256, 0, stream>>>((const float*)d_in[20], (const float*)d_in[21],
                                     (const float*)d_in[14], (const float*)d_in[15],
                                     (const float*)d_in[24], (const float*)d_in[25],
                                     (const float*)d_in[16], (const float*)d_in[17],
                                     (const float*)d_in[28], (const float*)d_in[29],
                                     (const float*)d_in[18], (const float*)d_in[19],
                                     WqF, bqF, WvF, bvF, W1F, b1F);
  st_cvt<<<64,  256, 0, stream>>>((const float*)d_in[10], egoWB, 16384);
  st_cvt<<<192, 256, 0, stream>>>((const float*)d_in[26], WoB,   49152);
  st_cvt<<<768, 256, 0, stream>>>((const float*)d_in[30], W2B,  196608);
  st_cvt<<<64,  256, 0, stream>>>((const float*)d_in[32], outWB, 16384);

  P p;
  p.ego_ctx=(const float*)d_in[0];  p.ego_pos=(const float*)d_in[1];  p.ego_vel=(const float*)d_in[2];
  p.npos=(const float*)d_in[3];     p.nvel=(const float*)d_in[4];     p.mask=(const int*)d_in[5];
  p.np_W=(const float*)d_in[6];     p.np_b=(const float*)d_in[7];     p.np_g=(const float*)d_in[8];   p.np_bb=(const float*)d_in[9];
  p.ego_b=(const float*)d_in[11];   p.ego_g=(const float*)d_in[12];   p.ego_bb=(const float*)d_in[13];
  p.bo=(const float*)d_in[27];      p.b2=(const float*)d_in[31];
  p.out_b=(const float*)d_in[33];   p.out_g=(const float*)d_in[34];   p.out_bb=(const float*)d_in[35];
  p.egoWB=egoWB; p.WoB=WoB; p.W2B=W2B; p.outWB=outWB;
  p.WqF=WqF; p.WkT=WkT; p.WvF=WvF; p.W1F=W1F;
  p.bqF=bqF; p.bkF=bkF; p.bvF=bvF; p.b1F=b1F;
  p.out=(float*)d_out;
  st_main<<<B_/2, 256, 0, stream>>>(p);
}

// Round 3
// 618.821 us; speedup vs baseline: 2.1472x; 2.1472x over previous
//
#include <hip/hip_runtime.h>
#include <stdint.h>

typedef unsigned int uint;
typedef unsigned short ushort;
typedef unsigned long long u64;

#define B_   8192
#define D_   128
#define N_   64
#define L_   3

typedef __attribute__((ext_vector_type(8))) short short8;
typedef __attribute__((ext_vector_type(4))) float f32x4;
union FragU { uint4 u; short8 h; };

__device__ __forceinline__ float bf2f(ushort u){ union{uint i; float f;} c; c.i=((uint)u)<<16; return c.f; }
__device__ __forceinline__ float bflo(uint u){ union{uint i; float f;} c; c.i=u<<16; return c.f; }
__device__ __forceinline__ float bfhi(uint u){ union{uint i; float f;} c; c.i=u&0xffff0000u; return c.f; }
__device__ __forceinline__ ushort f2bf(float f){ uint u=__float_as_uint(f); return (ushort)((u + 0x7fffu + ((u>>16)&1u))>>16); }
__device__ __forceinline__ uint pk2(float lo, float hi){ return (uint)f2bf(lo) | (((uint)f2bf(hi))<<16); }
__device__ __forceinline__ float wsum(float v){ for (int o=32;o;o>>=1) v += __shfl_xor(v,o); return v; }

// ---------------- LDS layout (bytes) ----------------
#define OFF_X   0        // x residual: f32 [16][130]  (stride 520 B)
#define XSTR    520
#define OFF_XH  8320     // A operand bf16 [16][136]   (stride 272 B, 16B-aligned frags)
#define XHSTR   272
#define OFF_Q   12672    // Q bf16 [16][130] (stride 260 B)
#define QSTR    260
#define OFF_QK  16832    // qk bf16 [16][136] (rows 8..15 zeroed once)
#define QKSTR   272
#define OFF_QB  21184    // qb f32 [16] (rows 8..15 zero)
#define OFF_V   21248    // valid flags f32 [64]
#define OFF_NB  21504    // nbhat n-major bf16 [64][136]
#define NBSTR   272
#define OFF_NT  38912    // nbhat d-major bf16 [128][72]
#define NTSTR   144
#define OFF_AT  57344    // attn bf16 [16][72]
#define ATSTR   144
#define OFF_U   59648    // U bf16 [8][132]
#define OFF_CX  61760    // ctx f32 [128]
#define OFF_H1  21504    // h1 bf16 [16][520] — aliases NB region (FFN phase only)
#define LDS_SZ  62272

struct P {
  const float *ego, *epos, *evel, *npos, *nvel;
  const int   *mask;
  const float *npW, *npb, *npg, *npbb;
  const float *ego_b, *ego_g, *ego_bb;
  const float *bo, *b2, *out_b, *out_g, *out_bb;
  const float *npRec;
  const ushort *WqT, *WkT, *WvT, *W1T, *WoT, *W2T, *egoT, *outT;
  const ushort *bqF, *bkF, *bvF, *b1F;
  ushort *nbg; u64 *msk;
  float *outp;
};

// ---------------- prep: fold (LN-gamma into rows) + transpose + bias-fold ----------------
__global__ void prepF(const float* Wq,const float* bq,const float* n1g,const float* n1b,
                      const float* Wk,const float* bk,const float* nkg,const float* nkb,
                      const float* Wv,const float* bv,
                      const float* W1,const float* b1,const float* n2g,const float* n2b,
                      ushort* WqT, ushort* bqF, ushort* WkT, ushort* bkF,
                      ushort* WvT, ushort* bvF, ushort* W1T, ushort* b1F){
  __shared__ float red[2];
  int bid=blockIdx.x, t=threadIdx.x;
  const float *src,*g,*bb,*bias; ushort *dstW,*dstB; int N;
  if (bid<384){ int l=bid>>7, j=bid&127; src=Wq+l*16384+j; g=n1g+l*128; bb=n1b+l*128; bias=bq+l*128+j; dstW=WqT+l*16384+j*128; dstB=bqF+l*128+j; N=128; }
  else if (bid<768){ int q=bid-384; int l=q>>7, j=q&127; src=Wk+l*16384+j; g=nkg+l*128; bb=nkb+l*128; bias=bk+l*128+j; dstW=WkT+l*16384+j*128; dstB=bkF+l*128+j; N=128; }
  else if (bid<1152){ int q=bid-768; int l=q>>7, j=q&127; src=Wv+l*16384+j; g=nkg+l*128; bb=nkb+l*128; bias=bv+l*128+j; dstW=WvT+l*16384+j*128; dstB=bvF+l*128+j; N=128; }
  else { int q=bid-1152; int l=q/512, j=q%512; src=W1+l*65536+j; g=n2g+l*128; bb=n2b+l*128; bias=b1+l*512+j; dstW=W1T+l*65536+j*128; dstB=b1F+l*512+j; N=512; }
  float wv = src[t*N];
  dstW[t] = f2bf(g[t]*wv);
  float pv = wsum(bb[t]*wv);
  if ((t&63)==0) red[t>>6]=pv;
  __syncthreads();
  if (t==0) *dstB = f2bf(red[0]+red[1]+bias[0]);
}

__global__ void prepP(const float* Wo, const float* W2, const float* egoW, const float* outW,
                      ushort* WoT, ushort* W2T, ushort* egoT, ushort* outT){
  int bid=blockIdx.x, t=threadIdx.x;
  if (bid<384){ int l=bid>>7, j=bid&127; WoT[l*16384+j*128+t] = f2bf(Wo[l*16384+t*128+j]); }
  else if (bid<768){ int q=bid-384; int l=q>>7, j=q&127;
    for (int k=t;k<512;k+=128) W2T[l*65536+j*512+k] = f2bf(W2[l*65536+k*128+j]); }
  else if (bid<896){ int j=bid-768; egoT[j*128+t]=f2bf(egoW[t*128+j]); }
  else { int j=bid-896; outT[j*128+t]=f2bf(outW[t*128+j]); }
}

__global__ void prepNp(const float* npW, const float* npb, const float* npg, const float* npbb, float* rec){
  int t=threadIdx.x;
  if (t<128){
    for (int r=0;r<6;++r) rec[t*9+r]=npW[r*128+t];
    rec[t*9+6]=npb[t]; rec[t*9+7]=npg[t]; rec[t*9+8]=npbb[t];
  }
}

// ---------------- st_nb (spill path): nbhat -> ws, mask -> ws ----------------
__global__ __launch_bounds__(256,4) void st_nb(P p){
  __shared__ float s_npW[768], s_npP[384];
  __shared__ float s_valid[2][64];
  int tid=threadIdx.x, g=tid>>7, t=tid&127;
  int b = blockIdx.x*2+g;
  for (int i=tid;i<768;i+=256) s_npW[i]=p.npW[i];
  if (tid<128){ s_npP[tid]=p.npb[tid]; s_npP[128+tid]=p.npg[tid]; s_npP[256+tid]=p.npbb[tid]; }
  __syncthreads();
  int nn=t>>1, jh=t&1;
  float2 pn = ((const float2*)p.npos)[b*N_+nn];
  float2 vn = ((const float2*)p.nvel)[b*N_+nn];
  float2 pe = ((const float2*)p.epos)[b];
  float2 ve = ((const float2*)p.evel)[b];
  float rx=pn.x-pe.x, ry=pn.y-pe.y, rvx=vn.x-ve.x, rvy=vn.y-ve.y;
  float nrm = sqrtf(rx*rx+ry*ry);
  float dist = fmaxf(nrm,1e-6f), bear = atan2f(ry+1e-8f, rx+1e-8f);
  bool vld = (p.mask[b*N_+nn]!=0) && (nrm<3.0f);
  if (jh==0) s_valid[g][nn] = vld?1.f:0.f;
  float z[64]; float sa=0.f, sb=0.f;
  #pragma unroll
  for (int jj=0;jj<64;++jj){
    int j = jh*64+jj;
    float v = s_npP[j] + rx*s_npW[j] + ry*s_npW[128+j] + rvx*s_npW[256+j]
                       + rvy*s_npW[384+j] + dist*s_npW[512+j] + bear*s_npW[640+j];
    z[jj]=v; sa+=v; sb+=v*v;
  }
  sa += __shfl_xor(sa,1); sb += __shfl_xor(sb,1);
  float m1 = sa*0.0078125f, r1 = rsqrtf(sb*0.0078125f - m1*m1 + 1e-5f);
  float ta=0.f, tb=0.f;
  #pragma unroll
  for (int jj=0;jj<64;++jj){
    int j = jh*64+jj;
    float a = (z[jj]-m1)*r1*s_npP[128+j] + s_npP[256+j];
    a = fmaxf(a,0.f);
    z[jj]=a; ta+=a; tb+=a*a;
  }
  ta += __shfl_xor(ta,1); tb += __shfl_xor(tb,1);
  float m2 = ta*0.0078125f, r2 = rsqrtf(tb*0.0078125f - m2*m2 + 1e-5f);
  uint* dst = (uint*)(p.nbg + (size_t)b*8192 + nn*128 + jh*64);
  #pragma unroll
  for (int q=0;q<32;++q) dst[q] = pk2((z[2*q]-m2)*r2, (z[2*q+1]-m2)*r2);
  __syncthreads();
  if (tid<2){
    u64 m=0;
    for (int n=0;n<64;++n) if (s_valid[tid][n]>0.5f) m |= (1ULL<<n);
    p.msk[blockIdx.x*2+tid] = m;
  }
}

// ---------------- main fused kernel ----------------
__device__ __forceinline__ void ln_to_xh(char* smem, int tid){
  int b = tid>>4, pp = tid&15;
  const char* xr = smem + OFF_X + b*XSTR + pp*32;
  float v[8];
  #pragma unroll
  for (int i=0;i<4;++i){ float2 t2 = *(const float2*)(xr + i*8); v[2*i]=t2.x; v[2*i+1]=t2.y; }
  float s1=0.f, s2=0.f;
  #pragma unroll
  for (int i=0;i<8;++i){ s1+=v[i]; s2+=v[i]*v[i]; }
  for (int o=1;o<16;o<<=1){ s1 += __shfl_xor(s1,o); s2 += __shfl_xor(s2,o); }
  float m = s1*0.0078125f, rs = rsqrtf(s2*0.0078125f - m*m + 1e-5f);
  uint4 o4;
  o4.x = pk2((v[0]-m)*rs,(v[1]-m)*rs); o4.y = pk2((v[2]-m)*rs,(v[3]-m)*rs);
  o4.z = pk2((v[4]-m)*rs,(v[5]-m)*rs); o4.w = pk2((v[6]-m)*rs,(v[7]-m)*rs);
  *(uint4*)(smem + OFF_XH + b*XHSTR + pp*16) = o4;
}

__device__ __forceinline__ void ln_affine_inplace(char* smem, int tid, const float* g, const float* bb){
  int b = tid>>4, pp = tid&15;
  char* xr = smem + OFF_X + b*XSTR + pp*32;
  float v[8];
  #pragma unroll
  for (int i=0;i<4;++i){ float2 t2 = *(const float2*)(xr + i*8); v[2*i]=t2.x; v[2*i+1]=t2.y; }
  float s1=0.f, s2=0.f;
  #pragma unroll
  for (int i=0;i<8;++i){ s1+=v[i]; s2+=v[i]*v[i]; }
  for (int o=1;o<16;o<<=1){ s1 += __shfl_xor(s1,o); s2 += __shfl_xor(s2,o); }
  float m = s1*0.0078125f, rs = rsqrtf(s2*0.0078125f - m*m + 1e-5f);
  #pragma unroll
  for (int i=0;i<8;++i) v[i] = (v[i]-m)*rs*g[pp*8+i] + bb[pp*8+i];
  #pragma unroll
  for (int i=0;i<4;++i){ float2 t2; t2.x=v[2*i]; t2.y=v[2*i+1]; *(float2*)(xr + i*8) = t2; }
}

__device__ __forceinline__ void cvt_x_to_xh(char* smem, int tid){
  int b = tid>>4, pp = tid&15;
  const char* xr = smem + OFF_X + b*XSTR + pp*32;
  float v[8];
  #pragma unroll
  for (int i=0;i<4;++i){ float2 t2 = *(const float2*)(xr + i*8); v[2*i]=t2.x; v[2*i+1]=t2.y; }
  uint4 o4;
  o4.x=pk2(v[0],v[1]); o4.y=pk2(v[2],v[3]); o4.z=pk2(v[4],v[5]); o4.w=pk2(v[6],v[7]);
  *(uint4*)(smem + OFF_XH + b*XHSTR + pp*16) = o4;
}

template<int SPILL>
__global__ __launch_bounds__(256,2) void st_main(P p){
  __shared__ __align__(16) char smem[LDS_SZ];
  const int tid = threadIdx.x;
  const int w = tid>>6, l64 = tid&63;
  const int cc = l64&15, qq = l64>>4;
  const int bB = blockIdx.x*16;

  // one-time zeroing: qk rows (all; 8..15 stay 0), qb, attn rows 8..15
  for (int i=tid;i<1088;i+=256) ((uint*)(smem+OFF_QK))[i]=0u;
  if (tid<16) ((float*)(smem+OFF_QB))[tid]=0.f;
  for (int i=tid;i<288;i+=256) ((uint*)(smem+OFF_AT+8*ATSTR))[i]=0u;

  // ego: cvt input -> xh
  {
    int b_=tid>>4, pp=tid&15;
    const float* src = p.ego + (size_t)(bB+b_)*128 + pp*8;
    float4 v0 = *(const float4*)src, v1 = *(const float4*)(src+4);
    uint4 o4; o4.x=pk2(v0.x,v0.y); o4.y=pk2(v0.z,v0.w); o4.z=pk2(v1.x,v1.y); o4.w=pk2(v1.z,v1.w);
    *(uint4*)(smem + OFF_XH + b_*XHSTR + pp*16) = o4;
  }
  __syncthreads();
  // ego GEMM -> x (f32, +ego_b)
  {
    #pragma unroll
    for (int i=0;i<2;++i){
      int nt = w*2+i;
      f32x4 acc = {0.f,0.f,0.f,0.f};
      #pragma unroll
      for (int kt=0;kt<4;++kt){
        FragU a,bF;
        a.u = *(const uint4*)(smem + OFF_XH + cc*XHSTR + kt*64 + qq*16);
        bF.u = *(const uint4*)(p.egoT + (nt*16+cc)*128 + kt*32 + qq*8);
        acc = __builtin_amdgcn_mfma_f32_16x16x32_bf16(a.h, bF.h, acc, 0,0,0);
      }
      int col = nt*16+cc;
      float bv = p.ego_b[col];
      #pragma unroll
      for (int r=0;r<4;++r) *(float*)(smem+OFF_X+(qq*4+r)*XSTR+col*4) = acc[r]+bv;
    }
  }
  __syncthreads();
  ln_affine_inplace(smem, tid, p.ego_g, p.ego_bb);
  __syncthreads();

  for (int li=0; li<L_; ++li){
    // LN(x) -> xh (n1 folded)
    ln_to_xh(smem, tid);
    __syncthreads();
    // Q GEMM
    {
      const ushort* W = p.WqT + li*16384;
      #pragma unroll
      for (int i=0;i<2;++i){
        int nt = w*2+i;
        f32x4 acc = {0.f,0.f,0.f,0.f};
        #pragma unroll
        for (int kt=0;kt<4;++kt){
          FragU a,bF;
          a.u = *(const uint4*)(smem + OFF_XH + cc*XHSTR + kt*64 + qq*16);
          bF.u = *(const uint4*)(W + (nt*16+cc)*128 + kt*32 + qq*8);
          acc = __builtin_amdgcn_mfma_f32_16x16x32_bf16(a.h, bF.h, acc, 0,0,0);
        }
        int col = nt*16+cc;
        float bv = bf2f(p.bqF[li*128+col]);
        ushort* Qm = (ushort*)(smem+OFF_Q);
        #pragma unroll
        for (int r=0;r<4;++r) Qm[(qq*4+r)*130 + col] = f2bf(acc[r]+bv);
      }
    }
    __syncthreads();

    // ---- attention rounds: 1 batch per round, 4 waves cooperate ----
    for (int bl=0; bl<16; ++bl){
      const int b = bB + bl;
      // stage nbhat (both layouts) + valid
      if (SPILL){
        int n = w*16 + (l64>>2), seg = l64&3;
        if (seg==0){
          u64 mv = p.msk[b];
          *(float*)(smem+OFF_V+n*4) = ((mv>>n)&1ULL) ? 1.f : 0.f;
        }
        const uint4* src = (const uint4*)(p.nbg + (size_t)b*8192 + n*128);
        ushort* T = (ushort*)(smem+OFF_NT);
        #pragma unroll
        for (int i=0;i<4;++i){
          int ci = seg + i*4;
          uint4 v = src[ci];
          *(uint4*)(smem + OFF_NB + n*NBSTR + ci*16) = v;
          int d0 = ci*8;
          T[(d0+0)*72+n]=(ushort)v.x; T[(d0+1)*72+n]=(ushort)(v.x>>16);
          T[(d0+2)*72+n]=(ushort)v.y; T[(d0+3)*72+n]=(ushort)(v.y>>16);
          T[(d0+4)*72+n]=(ushort)v.z; T[(d0+5)*72+n]=(ushort)(v.z>>16);
          T[(d0+6)*72+n]=(ushort)v.w; T[(d0+7)*72+n]=(ushort)(v.w>>16);
        }
      } else {
        int n = w*16 + (l64>>2), jq = l64&3;
        float2 pn = ((const float2*)p.npos)[b*N_+n];
        float2 vn = ((const float2*)p.nvel)[b*N_+n];
        float2 pe = ((const float2*)p.epos)[b];
        float2 ve = ((const float2*)p.evel)[b];
        float rx=pn.x-pe.x, ry=pn.y-pe.y, rvx=vn.x-ve.x, rvy=vn.y-ve.y;
        float nrm = sqrtf(rx*rx+ry*ry);
        float dist = fmaxf(nrm,1e-6f), bear = atan2f(ry+1e-8f, rx+1e-8f);
        if (jq==0){
          bool vld = (p.mask[b*N_+n]!=0) && (nrm<3.0f);
          *(float*)(smem+OFF_V+n*4) = vld?1.f:0.f;
        }
        float z[32]; float sa=0.f, sb=0.f;
        #pragma unroll
        for (int jj=0;jj<32;++jj){
          const float* rec = p.npRec + (jq*32+jj)*9;
          float4 r0 = *(const float4*)rec;
          float4 r1 = *(const float4*)(rec+4);
          float v = r1.z + rx*r0.x + ry*r0.y + rvx*r0.z + rvy*r0.w + dist*r1.x + bear*r1.y;
          z[jj]=v; sa+=v; sb+=v*v;
        }
        sa += __shfl_xor(sa,1); sb += __shfl_xor(sb,1);
        sa += __shfl_xor(sa,2); sb += __shfl_xor(sb,2);
        float m1 = sa*0.0078125f, r1s = rsqrtf(sb*0.0078125f - m1*m1 + 1e-5f);
        float ta=0.f, tb=0.f;
        #pragma unroll
        for (int jj=0;jj<32;++jj){
          const float* rec = p.npRec + (jq*32+jj)*9;
          float a = (z[jj]-m1)*r1s*rec[7] + rec[8];
          a = fmaxf(a,0.f);
          z[jj]=a; ta+=a; tb+=a*a;
        }
        ta += __shfl_xor(ta,1); tb += __shfl_xor(tb,1);
        ta += __shfl_xor(ta,2); tb += __shfl_xor(tb,2);
        float m2 = ta*0.0078125f, r2s = rsqrtf(tb*0.0078125f - m2*m2 + 1e-5f);
        ushort* T = (ushort*)(smem+OFF_NT);
        #pragma unroll
        for (int q2=0;q2<16;++q2){
          uint pr = pk2((z[2*q2]-m2)*r2s, (z[2*q2+1]-m2)*r2s);
          *(uint*)(smem + OFF_NB + n*NBSTR + jq*64 + q2*4) = pr;
          int d = jq*32 + q2*2;
          T[d*72 + n] = (ushort)pr;
          T[(d+1)*72 + n] = (ushort)(pr>>16);
        }
      }
      // qk fold: qk[h][d] = sum_j WkT'[h16+j][d] * Q[bl][h16+j]; qb[h]
      {
        int h = (w<<1) + (l64>>5);
        int d4 = (l64&31)*4;
        const ushort* Wk = p.WkT + li*16384;
        float a0=0.f,a1=0.f,a2=0.f,a3=0.f, qb=0.f;
        #pragma unroll
        for (int j=0;j<16;++j){
          float qv = bf2f(*(const ushort*)(smem + OFF_Q + bl*QSTR + (h*16+j)*2));
          uint2 wv = *(const uint2*)(Wk + (h*16+j)*128 + d4);
          a0 += qv*bflo(wv.x); a1 += qv*bfhi(wv.x);
          a2 += qv*bflo(wv.y); a3 += qv*bfhi(wv.y);
          qb += qv * bf2f(p.bkF[li*128 + h*16 + j]);
        }
        uint2 o; o.x = pk2(a0,a1); o.y = pk2(a2,a3);
        *(uint2*)(smem + OFF_QK + h*QKSTR + d4*2) = o;
        if ((l64&31)==0) *(float*)(smem+OFF_QB + h*4) = qb;
      }
      __syncthreads();

      // scores^T = nbhat @ qk^T via MFMA (redundant on 4 waves), softmax
      {
        FragU bfr[4];
        #pragma unroll
        for (int kt=0;kt<4;++kt) bfr[kt].u = *(const uint4*)(smem + OFF_QK + cc*QKSTR + kt*64 + qq*16);
        f32x4 c[4];
        #pragma unroll
        for (int mt=0;mt<4;++mt){
          f32x4 acc = {0.f,0.f,0.f,0.f};
          #pragma unroll
          for (int kt=0;kt<4;++kt){
            FragU a; a.u = *(const uint4*)(smem + OFF_NB + (mt*16+cc)*NBSTR + kt*64 + qq*16);
            acc = __builtin_amdgcn_mfma_f32_16x16x32_bf16(a.h, bfr[kt].h, acc, 0,0,0);
          }
          c[mt]=acc;
        }
        float qbv = *(const float*)(smem+OFF_QB+cc*4);
        float fl[16]; float anyv=0.f;
        #pragma unroll
        for (int mt=0;mt<4;++mt)
          #pragma unroll
          for (int r=0;r<4;++r){
            int n = mt*16 + qq*4 + r;
            float f = *(const float*)(smem+OFF_V+n*4);
            fl[mt*4+r]=f; anyv+=f;
          }
        bool none = (__ballot(anyv>0.5f)==0ULL);
        float sc[16];
        #pragma unroll
        for (int mt=0;mt<4;++mt)
          #pragma unroll
          for (int r=0;r<4;++r){
            int k = mt*4+r; int n = mt*16+qq*4+r;
            bool ok = (fl[k]>0.5f) || (none && n==0);
            sc[k] = ok ? 0.25f*(c[mt][r]+qbv) : -1e9f;
          }
        float mx=-3e38f;
        #pragma unroll
        for (int k=0;k<16;++k) mx=fmaxf(mx,sc[k]);
        mx = fmaxf(mx,__shfl_xor(mx,16)); mx = fmaxf(mx,__shfl_xor(mx,32));
        float ex[16]; float se=0.f;
        #pragma unroll
        for (int k=0;k<16;++k){ ex[k]=__expf(sc[k]-mx); se+=ex[k]; }
        se += __shfl_xor(se,16); se += __shfl_xor(se,32);
        float inv = 1.f/se;
        if (w==0 && cc<8){
          ushort* A = (ushort*)(smem+OFF_AT);
          #pragma unroll
          for (int mt=0;mt<4;++mt)
            #pragma unroll
            for (int r=0;r<4;++r) A[cc*72 + (mt*16+qq*4+r)] = f2bf(ex[mt*4+r]*inv);
        }
      }
      __syncthreads();

      // U = attn @ nbhat via MFMA (B from transposed copy)
      {
        #pragma unroll
        for (int i=0;i<2;++i){
          int nt = w*2 + i;
          f32x4 acc={0.f,0.f,0.f,0.f};
          #pragma unroll
          for (int kt=0;kt<2;++kt){
            FragU a,bF;
            a.u = *(const uint4*)(smem + OFF_AT + cc*ATSTR + kt*64 + qq*16);
            bF.u = *(const uint4*)(smem + OFF_NT + (nt*16+cc)*NTSTR + kt*64 + qq*16);
            acc = __builtin_amdgcn_mfma_f32_16x16x32_bf16(a.h, bF.h, acc, 0,0,0);
          }
          if (qq<2){
            ushort* U = (ushort*)(smem+OFF_U);
            #pragma unroll
            for (int r=0;r<4;++r) U[(qq*4+r)*132 + nt*16+cc] = f2bf(acc[r]);
          }
        }
      }
      __syncthreads();

      // ctx[j] = U[h(j)] . WvT'[j] + bvF[j]
      {
        int jj = l64>>1, dh = l64&1;
        int j = w*32 + jj;
        int h = j>>4;
        const ushort* Wv = p.WvT + li*16384 + j*128;
        float acc = (dh==0) ? bf2f(p.bvF[li*128+j]) : 0.f;
        #pragma unroll
        for (int i8=0;i8<8;++i8){
          int d = dh*64 + i8*8;
          uint2 u0 = *(const uint2*)(smem + OFF_U + h*264 + d*2);
          uint2 u1 = *(const uint2*)(smem + OFF_U + h*264 + d*2 + 8);
          uint4 wv = *(const uint4*)(Wv + d);
          acc += bflo(u0.x)*bflo(wv.x) + bfhi(u0.x)*bfhi(wv.x);
          acc += bflo(u0.y)*bflo(wv.y) + bfhi(u0.y)*bfhi(wv.y);
          acc += bflo(u1.x)*bflo(wv.z) + bfhi(u1.x)*bfhi(wv.z);
          acc += bflo(u1.y)*bflo(wv.w) + bfhi(u1.y)*bfhi(wv.w);
        }
        acc += __shfl_xor(acc,1);
        if (dh==0) *(float*)(smem+OFF_CX + j*4) = acc;
      }
      __syncthreads();

      // x[bl] += ctx @ WoT + bo
      {
        int jj = l64>>1, dh = l64&1;
        int j = w*32 + jj;
        const ushort* Wo = p.WoT + li*16384 + j*128;
        float acc = (dh==0) ? p.bo[li*128+j] : 0.f;
        #pragma unroll
        for (int i8=0;i8<8;++i8){
          int d = dh*64 + i8*8;
          float4 c0 = *(const float4*)(smem + OFF_CX + d*4);
          float4 c1 = *(const float4*)(smem + OFF_CX + d*4 + 16);
          uint4 wv = *(const uint4*)(Wo + d);
          acc += c0.x*bflo(wv.x) + c0.y*bfhi(wv.x) + c0.z*bflo(wv.y) + c0.w*bfhi(wv.y);
          acc += c1.x*bflo(wv.z) + c1.y*bfhi(wv.z) + c1.z*bflo(wv.w) + c1.w*bfhi(wv.w);
        }
        acc += __shfl_xor(acc,1);
        if (dh==0){
          float* xp = (float*)(smem + OFF_X + bl*XSTR + j*4);
          *xp += acc;
        }
      }
      __syncthreads();
    } // rounds

    // FFN: LN(x) -> xh (n2 folded)
    ln_to_xh(smem, tid);
    __syncthreads();
    // W1 GEMM + gelu -> h1
    {
      FragU afr[4];
      #pragma unroll
      for (int kt=0;kt<4;++kt) afr[kt].u = *(const uint4*)(smem+OFF_XH + cc*XHSTR + kt*64 + qq*16);
      const ushort* W = p.W1T + li*65536;
      ushort* H = (ushort*)(smem+OFF_H1);
      #pragma unroll
      for (int i=0;i<8;++i){
        int nt = w*8+i;
        f32x4 acc={0.f,0.f,0.f,0.f};
        #pragma unroll
        for (int kt=0;kt<4;++kt){
          FragU bF; bF.u = *(const uint4*)(W + (nt*16+cc)*128 + kt*32 + qq*8);
          acc = __builtin_amdgcn_mfma_f32_16x16x32_bf16(afr[kt].h, bF.h, acc, 0,0,0);
        }
        int col = nt*16+cc;
        float bv = bf2f(p.b1F[li*512+col]);
        #pragma unroll
        for (int r=0;r<4;++r){
          float v = acc[r]+bv;
          v = 0.5f*v*(1.f+erff(v*0.70710678118654752f));
          H[(qq*4+r)*520 + col] = f2bf(v);
        }
      }
    }
    __syncthreads();
    // W2 GEMM -> x +=
    {
      const ushort* W = p.W2T + li*65536;
      #pragma unroll
      for (int i=0;i<2;++i){
        int nt = w*2+i;
        f32x4 acc={0.f,0.f,0.f,0.f};
        #pragma unroll
        for (int kt=0;kt<16;++kt){
          FragU a,bF;
          a.u = *(const uint4*)(smem+OFF_H1 + cc*1040 + kt*64 + qq*16);
          bF.u = *(const uint4*)(W + (nt*16+cc)*512 + kt*32 + qq*8);
          acc = __builtin_amdgcn_mfma_f32_16x16x32_bf16(a.h, bF.h, acc, 0,0,0);
        }
        int col = nt*16+cc;
        float bv = p.b2[li*128+col];
        #pragma unroll
        for (int r=0;r<4;++r){
          float* xp = (float*)(smem+OFF_X+(qq*4+r)*XSTR+col*4);
          *xp += acc[r]+bv;
        }
      }
    }
    __syncthreads();
  } // layers

  // output: LN(x @ outW + out_b)
  cvt_x_to_xh(smem, tid);
  __syncthreads();
  {
    #pragma unroll
    for (int i=0;i<2;++i){
      int nt = w*2+i;
      f32x4 acc = {0.f,0.f,0.f,0.f};
      #pragma unroll
      for (int kt=0;kt<4;++kt){
        FragU a,bF;
        a.u = *(const uint4*)(smem + OFF_XH + cc*XHSTR + kt*64 + qq*16);
        bF.u = *(const uint4*)(p.outT + (nt*16+cc)*128 + kt*32 + qq*8);
        acc = __builtin_amdgcn_mfma_f32_16x16x32_bf16(a.h, bF.h, acc, 0,0,0);
      }
      int col = nt*16+cc;
      float bv = p.out_b[col];
      #pragma unroll
      for (int r=0;r<4;++r) *(float*)(smem+OFF_X+(qq*4+r)*XSTR+col*4) = acc[r]+bv;
    }
  }
  __syncthreads();
  {
    int b_=tid>>4, pp=tid&15;
    const char* xr = smem + OFF_X + b_*XSTR + pp*32;
    float v[8];
    #pragma unroll
    for (int i=0;i<4;++i){ float2 t2 = *(const float2*)(xr + i*8); v[2*i]=t2.x; v[2*i+1]=t2.y; }
    float s1=0.f, s2=0.f;
    #pragma unroll
    for (int i=0;i<8;++i){ s1+=v[i]; s2+=v[i]*v[i]; }
    for (int o=1;o<16;o<<=1){ s1 += __shfl_xor(s1,o); s2 += __shfl_xor(s2,o); }
    float m = s1*0.0078125f, rs = rsqrtf(s2*0.0078125f - m*m + 1e-5f);
    float4 o0,o1;
    o0.x=(v[0]-m)*rs*p.out_g[pp*8+0]+p.out_bb[pp*8+0];
    o0.y=(v[1]-m)*rs*p.out_g[pp*8+1]+p.out_bb[pp*8+1];
    o0.z=(v[2]-m)*rs*p.out_g[pp*8+2]+p.out_bb[pp*8+2];
    o0.w=(v[3]-m)*rs*p.out_g[pp*8+3]+p.out_bb[pp*8+3];
    o1.x=(v[4]-m)*rs*p.out_g[pp*8+4]+p.out_bb[pp*8+4];
    o1.y=(v[5]-m)*rs*p.out_g[pp*8+5]+p.out_bb[pp*8+5];
    o1.z=(v[6]-m)*rs*p.out_g[pp*8+6]+p.out_bb[pp*8+6];
    o1.w=(v[7]-m)*rs*p.out_g[pp*8+7]+p.out_bb[pp*8+7];
    float* dst = p.outp + (size_t)(bB+b_)*128 + pp*8;
    *(float4*)dst = o0; *(float4*)(dst+4) = o1;
  }
}

// ---------------- host ----------------
extern "C" void kernel_launch(void* const* d_in, const int* in_sizes, int n_in,
                              void* d_out, int out_size, void* d_ws, size_t ws_size,
                              hipStream_t stream){
  (void)in_sizes; (void)n_in; (void)out_size;
  char* ws = (char*)d_ws;
  // ws layout (bytes)
  ushort* WqT  = (ushort*)(ws + 0);
  ushort* WkT  = (ushort*)(ws + 98304);
  ushort* WvT  = (ushort*)(ws + 196608);
  ushort* W1T  = (ushort*)(ws + 294912);
  ushort* WoT  = (ushort*)(ws + 688128);
  ushort* W2T  = (ushort*)(ws + 786432);
  ushort* egoT = (ushort*)(ws + 1179648);
  ushort* outT = (ushort*)(ws + 1212416);
  float*  npRec= (float*) (ws + 1245184);  // 128*9*4 = 4608
  ushort* bqF  = (ushort*)(ws + 1249792);  // 768
  ushort* bkF  = (ushort*)(ws + 1250560);
  ushort* bvF  = (ushort*)(ws + 1251328);
  ushort* b1F  = (ushort*)(ws + 1252096);  // 3072 -> ends 1255168
  const size_t NB_OFF  = 1255424;
  const size_t MSK_OFF = NB_OFF + (size_t)B_*8192*2;       // 134 MB nbhat
  const size_t NEED    = MSK_OFF + (size_t)B_*8;
  const bool spill = (ws_size >= NEED);

  prepF<<<2688,128,0,stream>>>((const float*)d_in[20],(const float*)d_in[21],(const float*)d_in[14],(const float*)d_in[15],
                               (const float*)d_in[22],(const float*)d_in[23],(const float*)d_in[16],(const float*)d_in[17],
                               (const float*)d_in[24],(const float*)d_in[25],
                               (const float*)d_in[28],(const float*)d_in[29],(const float*)d_in[18],(const float*)d_in[19],
                               WqT,bqF,WkT,bkF,WvT,bvF,W1T,b1F);
  prepP<<<1024,128,0,stream>>>((const float*)d_in[26],(const float*)d_in[30],(const float*)d_in[10],(const float*)d_in[32],
                               WoT,W2T,egoT,outT);
  prepNp<<<1,128,0,stream>>>((const float*)d_in[6],(const float*)d_in[7],(const float*)d_in[8],(const float*)d_in[9],npRec);

  P p;
  p.ego=(const float*)d_in[0]; p.epos=(const float*)d_in[1]; p.evel=(const float*)d_in[2];
  p.npos=(const float*)d_in[3]; p.nvel=(const float*)d_in[4]; p.mask=(const int*)d_in[5];
  p.npW=(const float*)d_in[6]; p.npb=(const float*)d_in[7]; p.npg=(const float*)d_in[8]; p.npbb=(const float*)d_in[9];
  p.ego_b=(const float*)d_in[11]; p.ego_g=(const float*)d_in[12]; p.ego_bb=(const float*)d_in[13];
  p.bo=(const float*)d_in[27]; p.b2=(const float*)d_in[31];
  p.out_b=(const float*)d_in[33]; p.out_g=(const float*)d_in[34]; p.out_bb=(const float*)d_in[35];
  p.npRec=npRec;
  p.WqT=WqT; p.WkT=WkT; p.WvT=WvT; p.W1T=W1T; p.WoT=WoT; p.W2T=W2T; p.egoT=egoT; p.outT=outT;
  p.bqF=bqF; p.bkF=bkF; p.bvF=bvF; p.b1F=b1F;
  p.nbg = (ushort*)(ws + NB_OFF);
  p.msk = (u64*)(ws + MSK_OFF);
  p.outp=(float*)d_out;

  if (spill){
    st_nb<<<B_/2,256,0,stream>>>(p);
    st_main<1><<<B_/16,256,0,stream>>>(p);
  } else {
    st_main<0><<<B_/16,256,0,stream>>>(p);
  }
}